// Round 4
// baseline (517.915 us; speedup 1.0000x reference)
//
#include <hip/hip_runtime.h>
#include <cstdint>

// Problem constants
#define Bc 32
#define Lc 2048
#define Hc 512
#define Cc 50
#define PCc 52        // P3 row stride (52 floats = 208 B, 16B-aligned)
#define Mc (Bc*Lc)    // 65536 rows

typedef short s8v   __attribute__((ext_vector_type(8)));   // 8 bf16 (4 VGPRs)
typedef float f4v   __attribute__((ext_vector_type(4)));   // MFMA C/D

__device__ inline unsigned short f2bf(float f) {            // RNE fp32->bf16
    unsigned int u = __float_as_uint(f);
    u += 0x7fffu + ((u >> 16) & 1u);
    return (unsigned short)(u >> 16);
}
__device__ inline float bf2f(unsigned short h) {
    return __uint_as_float(((unsigned int)h) << 16);
}
// tanh(x) = 1 - 2/(e^{2x}+1): ~5 VALU ops (mul, v_exp, add, rcp, fma).
__device__ inline float fast_tanh(float x) {
    float e = __expf(2.0f * x);
    return 1.0f - 2.0f / (e + 1.0f);
}
__device__ inline void gl_lds16(const unsigned short* g, unsigned short* l) {
    __builtin_amdgcn_global_load_lds(
        (const __attribute__((address_space(1))) unsigned int*)g,
        (__attribute__((address_space(3))) unsigned int*)l, 16, 0, 0);
}

// ---------------------------------------------------------------------------
// fp32 -> bf16 bulk convert (keys). 8 elements/thread.
// ---------------------------------------------------------------------------
__global__ __launch_bounds__(256)
void f32_to_bf16_kernel(const float* __restrict__ in, unsigned short* __restrict__ out)
{
    size_t i = ((size_t)blockIdx.x * 256 + threadIdx.x) * 8;
    float4 a = *(const float4*)(in + i);
    float4 b = *(const float4*)(in + i + 4);
    s8v o;
    o[0]=f2bf(a.x); o[1]=f2bf(a.y); o[2]=f2bf(a.z); o[3]=f2bf(a.w);
    o[4]=f2bf(b.x); o[5]=f2bf(b.y); o[6]=f2bf(b.z); o[7]=f2bf(b.w);
    *(s8v*)(out + i) = o;
}

// ---------------------------------------------------------------------------
// Convert W1, W2 -> bf16; W3 (50x512) -> bf16 padded to 64x512 (zero rows).
// ---------------------------------------------------------------------------
__global__ __launch_bounds__(256)
void convert_weights_kernel(const float* __restrict__ W1, const float* __restrict__ W2,
                            const float* __restrict__ W3,
                            unsigned short* __restrict__ W1b,
                            unsigned short* __restrict__ W2b,
                            unsigned short* __restrict__ W3b)
{
    int e = (blockIdx.x * 256 + threadIdx.x) * 8;
    if (e >= 524288) {                       // W3 padded region
        int off = e - 524288;
        int row = off >> 9;
        s8v o;
        #pragma unroll
        for (int j = 0; j < 8; ++j)
            o[j] = (row < Cc) ? (short)f2bf(W3[off + j]) : (short)0;
        *(s8v*)(W3b + off) = o;
        return;
    }
    const float* src = (e < 262144) ? W1 : W2;
    unsigned short* dst = (e < 262144) ? W1b : W2b;
    int off = (e < 262144) ? e : e - 262144;
    float4 a = *(const float4*)(src + off);
    float4 b = *(const float4*)(src + off + 4);
    s8v o;
    o[0]=f2bf(a.x); o[1]=f2bf(a.y); o[2]=f2bf(a.z); o[3]=f2bf(a.w);
    o[4]=f2bf(b.x); o[5]=f2bf(b.y); o[6]=f2bf(b.z); o[7]=f2bf(b.w);
    *(s8v*)(dst + off) = o;
}

// ---------------------------------------------------------------------------
// V (fp32, [b][l][h]) -> Vt (bf16, [b][h][l]).  64x64 LDS tile transpose.
// Vectorized write side: 4 x ushort4 stores per thread.
// ---------------------------------------------------------------------------
__global__ __launch_bounds__(256)
void transpose_v_kernel(const float* __restrict__ V, unsigned short* __restrict__ Vt)
{
    __shared__ float tile[64 * 65];
    const int l0 = blockIdx.x * 64;
    const int h0 = blockIdx.y * 64;
    const int b  = blockIdx.z;
    const int tid = threadIdx.x;
    const int li = tid >> 2;          // 0..63
    const int hq = (tid & 3) * 4;     // 0,4,8,12

    const float* src = V + ((size_t)(b * Lc + l0 + li)) * Hc + h0 + hq;
    #pragma unroll
    for (int j = 0; j < 4; ++j) {
        float4 v = *(const float4*)(src + 16 * j);
        float* d = &tile[li * 65 + hq + 16 * j];
        d[0] = v.x; d[1] = v.y; d[2] = v.z; d[3] = v.w;
    }
    __syncthreads();

    const int lane = tid & 63;
    const int w4   = tid >> 6;
    const int lpos = (lane & 15) * 4;          // 4 consecutive l per lane
    #pragma unroll
    for (int i = 0; i < 4; ++i) {
        int hr = i * 16 + w4 * 4 + (lane >> 4);   // 0..63, unique per (i,w4,hi)
        ushort4 o;
        o.x = f2bf(tile[(lpos + 0) * 65 + hr]);
        o.y = f2bf(tile[(lpos + 1) * 65 + hr]);
        o.z = f2bf(tile[(lpos + 2) * 65 + hr]);
        o.w = f2bf(tile[(lpos + 3) * 65 + hr]);
        *(ushort4*)(Vt + ((size_t)(b * Hc + h0 + hr)) * Lc + l0 + lpos) = o;
    }
}

// ---------------------------------------------------------------------------
// MFMA GEMM: Out = f(A @ W^T), 128x128 tile.
// mode 0: Out = bf16(fast_tanh(acc)); mode 1: Out = bf16(A[m,j]+fast_tanh(acc))
//
// Round-4: BK=64 as TWO independent [128][32] half-tiles (identical bank
// behavior / lane maps to the proven BK=32 layout — no new conflicts, no
// swizzle). Plain __syncthreads structure (round-3's hand-pinned waits
// regressed; compiler schedules the waits). Barrier-drain events: 16 -> 8.
// LDS exactly 32 KB (As 16K + Bs 16K; epilogue Esf 17K overlays dead arena)
// -> 5 blocks/CU by LDS (was 4 at 33 KB).
// ---------------------------------------------------------------------------
__global__ __launch_bounds__(256)
void mfma_gemm512(const unsigned short* __restrict__ Ab,
                  const unsigned short* __restrict__ Wb,
                  unsigned short* __restrict__ Ob, int mode)
{
    __shared__ alignas(16) char smem[32768];
    unsigned short* As = (unsigned short*)smem;           // [2][128*32] halves
    unsigned short* Bs = (unsigned short*)(smem + 16384); // [2][128*32] halves
    float* Esf = (float*)smem;                            // [32*133] epilogue overlay

    const int tid = threadIdx.x;
    const int w = tid >> 6, l = tid & 63;

    // XCD-grouped mapping: the 4 col-blocks sharing 128 A-rows stay on one XCD.
    const int bid = blockIdx.x;
    const int ixd = bid >> 3;                 // 0..255 within XCD
    const int y   = (bid & 7) * 64 + (ixd >> 2);
    const int x   = ixd & 3;
    const int j0 = x * 128;
    const int i0 = y * 128;

    const int sr  = w * 16 + (l >> 2);
    const int kg8 = (l & 3) * 8;
    const unsigned short* Ag0 = Ab + (size_t)(i0 + sr) * 512 + kg8;
    const unsigned short* Ag1 = Ag0 + (size_t)64 * 512;
    const unsigned short* Bg0 = Wb + (size_t)(j0 + sr) * 512 + kg8;
    const unsigned short* Bg1 = Bg0 + (size_t)64 * 512;

    const int wm = (w & 1) * 64, wn = (w >> 1) * 64;
    const int fr = l & 15;
    const int fq = (l >> 4) * 8;

    f4v acc[4][4];
    #pragma unroll
    for (int r = 0; r < 4; ++r)
        #pragma unroll
        for (int c = 0; c < 4; ++c) acc[r][c] = (f4v){0.f, 0.f, 0.f, 0.f};

    for (int k0 = 0; k0 < 512; k0 += 64) {
        #pragma unroll
        for (int h = 0; h < 2; ++h) {
            gl_lds16(Ag0 + k0 + h * 32, As + h * 4096 + w * 512);
            gl_lds16(Ag1 + k0 + h * 32, As + h * 4096 + 2048 + w * 512);
            gl_lds16(Bg0 + k0 + h * 32, Bs + h * 4096 + w * 512);
            gl_lds16(Bg1 + k0 + h * 32, Bs + h * 4096 + 2048 + w * 512);
        }
        __syncthreads();
        #pragma unroll
        for (int h = 0; h < 2; ++h) {
            s8v af[4], bv[4];
            #pragma unroll
            for (int r = 0; r < 4; ++r)
                af[r] = *(const s8v*)&As[h * 4096 + (wm + r * 16 + fr) * 32 + fq];
            #pragma unroll
            for (int c = 0; c < 4; ++c)
                bv[c] = *(const s8v*)&Bs[h * 4096 + (wn + c * 16 + fr) * 32 + fq];
            #pragma unroll
            for (int r = 0; r < 4; ++r)
                #pragma unroll
                for (int c = 0; c < 4; ++c)
                    acc[r][c] = __builtin_amdgcn_mfma_f32_16x16x32_bf16(
                        af[r], bv[c], acc[r][c], 0, 0, 0);
        }
        __syncthreads();
    }

    // Vectorized epilogue: 4 quarter-phases, fp32 Esf -> coalesced ushort4.
    // Esf overlays the staging arena (dead; final __syncthreads separates).
    #pragma unroll
    for (int h = 0; h < 4; ++h) {
        if (h) __syncthreads();
        if ((w & 1) == (h >> 1)) {
            const int rr = (h & 1) * 2;
            #pragma unroll
            for (int r = 0; r < 2; ++r)
                #pragma unroll
                for (int c = 0; c < 4; ++c)
                    #pragma unroll
                    for (int v = 0; v < 4; ++v) {
                        int row = r * 16 + (l >> 4) * 4 + v;   // 0..31
                        int col = wn + c * 16 + fr;            // 0..127
                        Esf[row * 133 + col] = fast_tanh(acc[rr + r][c][v]);
                    }
        }
        __syncthreads();
        #pragma unroll
        for (int t = 0; t < 4; ++t) {
            int chunk = t * 256 + tid;       // 0..1023
            int row = chunk >> 5;            // 0..31
            int c4  = (chunk & 31) * 4;      // 0..124
            f4v val = *(const f4v*)&Esf[row * 133 + c4];
            size_t gr   = (size_t)(i0 + (h >> 1) * 64 + (h & 1) * 32 + row);
            size_t goff = gr * 512 + j0 + c4;
            ushort4 o;
            if (mode) {
                ushort4 a = *(const ushort4*)(Ab + goff);
                o.x = f2bf(val[0] + bf2f(a.x));
                o.y = f2bf(val[1] + bf2f(a.y));
                o.z = f2bf(val[2] + bf2f(a.z));
                o.w = f2bf(val[3] + bf2f(a.w));
            } else {
                o.x = f2bf(val[0]); o.y = f2bf(val[1]);
                o.z = f2bf(val[2]); o.w = f2bf(val[3]);
            }
            *(ushort4*)(Ob + goff) = o;
        }
    }
}

// ---------------------------------------------------------------------------
// MFMA GEMM3: P3 = S @ W3^T (N=50 padded 64), fp32 out, row stride PCc=52.
// Round-4: BK=64 via two half-tiles, plain syncs, 8 iters. LDS 24 KB.
// ---------------------------------------------------------------------------
__global__ __launch_bounds__(256)
void mfma_gemm_p3(const unsigned short* __restrict__ Sb,
                  const unsigned short* __restrict__ W3b,
                  float* __restrict__ P3)
{
    __shared__ alignas(16) char smem[24576];
    unsigned short* As = (unsigned short*)smem;           // [2][128*32]
    unsigned short* Bs = (unsigned short*)(smem + 16384); // [2][64*32]

    const int tid = threadIdx.x;
    const int w = tid >> 6, l = tid & 63;
    const int i0 = blockIdx.x * 128;

    const int sr  = w * 16 + (l >> 2);
    const int kg8 = (l & 3) * 8;
    const unsigned short* Ag0 = Sb + (size_t)(i0 + sr) * 512 + kg8;
    const unsigned short* Ag1 = Ag0 + (size_t)64 * 512;
    const unsigned short* Bg  = W3b + (size_t)sr * 512 + kg8;

    const int wm = w * 32;
    const int fr = l & 15;
    const int fq = (l >> 4) * 8;

    f4v acc[2][4];
    #pragma unroll
    for (int r = 0; r < 2; ++r)
        #pragma unroll
        for (int c = 0; c < 4; ++c) acc[r][c] = (f4v){0.f, 0.f, 0.f, 0.f};

    for (int k0 = 0; k0 < 512; k0 += 64) {
        #pragma unroll
        for (int h = 0; h < 2; ++h) {
            gl_lds16(Ag0 + k0 + h * 32, As + h * 4096 + w * 512);
            gl_lds16(Ag1 + k0 + h * 32, As + h * 4096 + 2048 + w * 512);
            gl_lds16(Bg  + k0 + h * 32, Bs + h * 2048 + w * 512);
        }
        __syncthreads();
        #pragma unroll
        for (int h = 0; h < 2; ++h) {
            s8v af[2], bv[4];
            #pragma unroll
            for (int r = 0; r < 2; ++r)
                af[r] = *(const s8v*)&As[h * 4096 + (wm + r * 16 + fr) * 32 + fq];
            #pragma unroll
            for (int c = 0; c < 4; ++c)
                bv[c] = *(const s8v*)&Bs[h * 2048 + (c * 16 + fr) * 32 + fq];
            #pragma unroll
            for (int r = 0; r < 2; ++r)
                #pragma unroll
                for (int c = 0; c < 4; ++c)
                    acc[r][c] = __builtin_amdgcn_mfma_f32_16x16x32_bf16(
                        af[r], bv[c], acc[r][c], 0, 0, 0);
        }
        __syncthreads();
    }

    #pragma unroll
    for (int r = 0; r < 2; ++r)
        #pragma unroll
        for (int v = 0; v < 4; ++v) {
            const int row = i0 + wm + r * 16 + (l >> 4) * 4 + v;
            #pragma unroll
            for (int c = 0; c < 4; ++c) {
                const int col = c * 16 + fr;
                if (col < Cc) P3[(size_t)row * PCc + col] = acc[r][c][v];
            }
        }
}

// ---------------------------------------------------------------------------
// sent_lens dtype hedge (int64 vs int32 auto-detect).
// ---------------------------------------------------------------------------
__global__ __launch_bounds__(64)
void normalize_lens_kernel(const int* __restrict__ raw, int* __restrict__ lens)
{
    __shared__ int is64;
    if (threadIdx.x == 0) {
        int orv = 0;
        for (int i = 1; i < 32; i += 2) orv |= raw[i];
        is64 = (orv == 0) ? 1 : 0;
    }
    __syncthreads();
    int b = threadIdx.x;
    if (b < Bc) lens[b] = is64 ? raw[2*b] : raw[b];
}

// ---------------------------------------------------------------------------
// kq-fill + avgpool3(count_include_pad=False) + softmax + mask.
// ---------------------------------------------------------------------------
__global__ __launch_bounds__(256)
void pool_softmax_kernel(const float* __restrict__ P3, const int* __restrict__ lens,
                         float* __restrict__ out_attn, float* __restrict__ out_smooth,
                         unsigned short* __restrict__ attnT)
{
    const int idx = blockIdx.x * 256 + threadIdx.x;   // b*L + l
    const int b = idx >> 11;
    const int l = idx & (Lc - 1);
    const int len = lens[b];
    const float* base = P3 + (size_t)b * Lc * PCc;

    const int  r0 = min(l, len - 1);
    const bool hm = (l > 0);
    const bool hp = (l < Lc - 1);
    const int  rm = hm ? min(l - 1, len - 1) : 0;
    const int  rp = hp ? min(l + 1, len - 1) : 0;
    const float rcnt = 1.f / (1.f + (hm ? 1.f : 0.f) + (hp ? 1.f : 0.f));

    float sm[PCc];
    const float* p0 = base + (size_t)r0 * PCc;
    #pragma unroll
    for (int q = 0; q < 13; ++q) {
        f4v v = *(const f4v*)(p0 + q * 4);
        sm[q*4+0] = v[0]; sm[q*4+1] = v[1]; sm[q*4+2] = v[2]; sm[q*4+3] = v[3];
    }
    if (hm) {
        const float* p = base + (size_t)rm * PCc;
        #pragma unroll
        for (int q = 0; q < 13; ++q) {
            f4v v = *(const f4v*)(p + q * 4);
            sm[q*4+0] += v[0]; sm[q*4+1] += v[1]; sm[q*4+2] += v[2]; sm[q*4+3] += v[3];
        }
    }
    if (hp) {
        const float* p = base + (size_t)rp * PCc;
        #pragma unroll
        for (int q = 0; q < 13; ++q) {
            f4v v = *(const f4v*)(p + q * 4);
            sm[q*4+0] += v[0]; sm[q*4+1] += v[1]; sm[q*4+2] += v[2]; sm[q*4+3] += v[3];
        }
    }

    float mx = -1e30f;
    #pragma unroll
    for (int c = 0; c < Cc; ++c) {
        sm[c] *= rcnt;
        mx = fmaxf(mx, sm[c]);
    }
    float* srow = out_smooth + (size_t)idx * Cc;
    #pragma unroll
    for (int q = 0; q < 25; ++q) {
        float2 v = make_float2(sm[q*2], sm[q*2+1]);
        *(float2*)(srow + q * 2) = v;
    }

    float sum = 0.f;
    #pragma unroll
    for (int c = 0; c < Cc; ++c) {
        float e = __expf(sm[c] - mx);
        sm[c] = e;
        sum += e;
    }
    const float inv = 1.f / sum;
    const bool valid = (l < len);
    const float scale = valid ? inv : 0.f;
    float* arow = out_attn + (size_t)idx * Cc;
    unsigned short* trow = attnT + (size_t)b * 64 * Lc + l;
    #pragma unroll
    for (int c = 0; c < Cc; ++c) sm[c] *= scale;
    #pragma unroll
    for (int q = 0; q < 25; ++q)
        *(float2*)(arow + q * 2) = make_float2(sm[q*2], sm[q*2+1]);
    #pragma unroll
    for (int c = 0; c < Cc; ++c)
        trow[(size_t)c * Lc] = f2bf(sm[c]);
}

// ---------------------------------------------------------------------------
// class_inputs[b,c,h] = sum_l attn[b,l,c] * V[b,l,h]  -- MFMA.
// XCD-grouped linear grid (512 blocks); BK=64 via half-tiles (8 iters/split).
// ---------------------------------------------------------------------------
__global__ __launch_bounds__(256)
void class_mfma_kernel(const unsigned short* __restrict__ attnT,
                       const unsigned short* __restrict__ Vt,
                       float* __restrict__ out_class)
{
    __shared__ alignas(16) char smem[24576];
    unsigned short* As = (unsigned short*)smem;          // [2][64*32]
    unsigned short* Bs = (unsigned short*)(smem + 8192); // [2][128*32]

    const int tid = threadIdx.x;
    const int w = tid >> 6, l = tid & 63;

    const int bid  = blockIdx.x;              // 0..511
    const int ixd  = bid >> 3;                // 0..63 within XCD
    const int pair = (bid & 7) * 16 + (ixd >> 2);   // 0..127 = (b,z)
    const int n0 = (ixd & 3) * 128;
    const int b  = pair >> 2;
    const int kb = (pair & 3) * 512;

    const int sr  = w * 16 + (l >> 2);   // 0..63
    const int kg8 = (l & 3) * 8;
    const unsigned short* Ag  = attnT + ((size_t)b * 64 + sr) * Lc + kg8;
    const unsigned short* Bg0 = Vt + ((size_t)(b * Hc + n0 + sr)) * Lc + kg8;
    const unsigned short* Bg1 = Bg0 + (size_t)64 * Lc;

    const int fr = l & 15;
    const int fq = (l >> 4) * 8;

    f4v acc[4][2];
    #pragma unroll
    for (int r = 0; r < 4; ++r)
        #pragma unroll
        for (int c = 0; c < 2; ++c) acc[r][c] = (f4v){0.f, 0.f, 0.f, 0.f};

    for (int k0 = kb; k0 < kb + 512; k0 += 64) {
        #pragma unroll
        for (int h = 0; h < 2; ++h) {
            gl_lds16(Ag  + k0 + h * 32, As + h * 2048 + w * 512);
            gl_lds16(Bg0 + k0 + h * 32, Bs + h * 4096 + w * 512);
            gl_lds16(Bg1 + k0 + h * 32, Bs + h * 4096 + 2048 + w * 512);
        }
        __syncthreads();
        #pragma unroll
        for (int h = 0; h < 2; ++h) {
            s8v af[4], bv[2];
            #pragma unroll
            for (int r = 0; r < 4; ++r)
                af[r] = *(const s8v*)&As[h * 2048 + (r * 16 + fr) * 32 + fq];
            #pragma unroll
            for (int c = 0; c < 2; ++c)
                bv[c] = *(const s8v*)&Bs[h * 4096 + (w * 32 + c * 16 + fr) * 32 + fq];
            #pragma unroll
            for (int r = 0; r < 4; ++r)
                #pragma unroll
                for (int c = 0; c < 2; ++c)
                    acc[r][c] = __builtin_amdgcn_mfma_f32_16x16x32_bf16(
                        af[r], bv[c], acc[r][c], 0, 0, 0);
        }
        __syncthreads();
    }

    #pragma unroll
    for (int r = 0; r < 4; ++r)
        #pragma unroll
        for (int v = 0; v < 4; ++v) {
            const int m = r * 16 + (l >> 4) * 4 + v;   // class index
            if (m < Cc) {
                #pragma unroll
                for (int c = 0; c < 2; ++c) {
                    const int h = n0 + w * 32 + c * 16 + fr;
                    atomicAdd(out_class + ((size_t)b * Cc + m) * Hc + h,
                              acc[r][c][v]);
                }
            }
        }
}

// ---------------------------------------------------------------------------
// Workspace layout (~203 MiB, overlays exploit stream ordering):
//   off 0      : Akv bf16 (64 MiB)      -> later P3 fp32 stride-52 (13.6 MiB)
//   off 64 MiB : P1b bf16 (64 MiB)      -> later Vt bf16 (64 MiB)
//   off 128 MiB: Sb  bf16 (64 MiB)
//   off 192 MiB: W1b, W2b (0.5 MiB each), W3b (64 KiB)
//   off 194 MiB: attnT bf16 32x64x2048 (8 MiB)
//   off 202 MiB: lens (128 B)
// ---------------------------------------------------------------------------
extern "C" void kernel_launch(void* const* d_in, const int* in_sizes, int n_in,
                              void* d_out, int out_size, void* d_ws, size_t ws_size,
                              hipStream_t stream)
{
    const float* keys     = (const float*)d_in[0];
    const float* vals     = (const float*)d_in[1];
    const int*   lens_raw = (const int*)d_in[2];
    const float* W1       = (const float*)d_in[3];
    const float* W2       = (const float*)d_in[4];
    const float* W3       = (const float*)d_in[5];

    char* ws = (char*)d_ws;
    const size_t MB = 1024 * 1024;
    unsigned short* Akv  = (unsigned short*)ws;
    float*          P3   = (float*)ws;                       // over Akv (dead)
    unsigned short* P1b  = (unsigned short*)(ws + 64 * MB);
    unsigned short* Vt   = (unsigned short*)(ws + 64 * MB);  // over P1b (dead)
    unsigned short* Sb   = (unsigned short*)(ws + 128 * MB);
    unsigned short* W1b  = (unsigned short*)(ws + 192 * MB);
    unsigned short* W2b  = W1b + Hc * Hc;
    unsigned short* W3b  = W2b + Hc * Hc;
    unsigned short* attnT= (unsigned short*)(ws + 194 * MB);
    int*            lens = (int*)(ws + 202 * MB);

    float* out_attn   = (float*)d_out;
    float* out_class  = out_attn + (size_t)Bc * Lc * Cc;
    float* out_smooth = out_class + (size_t)Bc * Cc * Hc;

    hipMemsetAsync(out_class, 0, (size_t)Bc * Cc * Hc * sizeof(float), stream);

    f32_to_bf16_kernel<<<(Mc * Hc / 8) / 256, 256, 0, stream>>>(keys, Akv);
    convert_weights_kernel<<<272, 256, 0, stream>>>(W1, W2, W3, W1b, W2b, W3b);
    normalize_lens_kernel<<<1, 64, 0, stream>>>(lens_raw, lens);

    // P1 = tanh(keys @ W1^T)   [bf16 out]
    mfma_gemm512<<<2048, 256, 0, stream>>>(Akv, W1b, P1b, 0);
    // S = P1 + tanh(P1 @ W2^T) [bf16 out]
    mfma_gemm512<<<2048, 256, 0, stream>>>(P1b, W2b, Sb, 1);
    // Vt = transpose(bf16(vals))  (P1b dead now; Vt overlays it)
    transpose_v_kernel<<<dim3(Lc / 64, Hc / 64, Bc), 256, 0, stream>>>(vals, Vt);
    // P3 = S @ W3^T            [fp32 out, stride 52, overlays dead Akv]
    mfma_gemm_p3<<<Mc / 128, 256, 0, stream>>>(Sb, W3b, P3);
    // pool + softmax + mask; also emits attnT bf16
    pool_softmax_kernel<<<Mc / 256, 256, 0, stream>>>(P3, lens, out_attn, out_smooth, attnT);
    // class_inputs = attnT @ Vt^T per batch (MFMA, K-split 4, atomic reduce)
    class_mfma_kernel<<<512, 256, 0, stream>>>(attnT, Vt, out_class);
}

// Round 5
// 498.642 us; speedup vs baseline: 1.0387x; 1.0387x over previous
//
#include <hip/hip_runtime.h>
#include <cstdint>

// Problem constants
#define Bc 32
#define Lc 2048
#define Hc 512
#define Cc 50
#define PCc 52        // P3 row stride (52 floats = 208 B, 16B-aligned)
#define Mc (Bc*Lc)    // 65536 rows

typedef short s8v   __attribute__((ext_vector_type(8)));   // 8 bf16 (4 VGPRs)
typedef float f4v   __attribute__((ext_vector_type(4)));   // MFMA C/D

__device__ inline unsigned short f2bf(float f) {            // RNE fp32->bf16
    unsigned int u = __float_as_uint(f);
    u += 0x7fffu + ((u >> 16) & 1u);
    return (unsigned short)(u >> 16);
}
__device__ inline float bf2f(unsigned short h) {
    return __uint_as_float(((unsigned int)h) << 16);
}
// tanh(x) = 1 - 2/(e^{2x}+1): ~5 VALU ops (mul, v_exp, add, rcp, fma).
__device__ inline float fast_tanh(float x) {
    float e = __expf(2.0f * x);
    return 1.0f - 2.0f / (e + 1.0f);
}
__device__ inline void gl_lds16(const unsigned short* g, unsigned short* l) {
    __builtin_amdgcn_global_load_lds(
        (const __attribute__((address_space(1))) unsigned int*)g,
        (__attribute__((address_space(3))) unsigned int*)l, 16, 0, 0);
}

// ---------------------------------------------------------------------------
// fp32 -> bf16 bulk convert (keys). 8 elements/thread.
// ---------------------------------------------------------------------------
__global__ __launch_bounds__(256)
void f32_to_bf16_kernel(const float* __restrict__ in, unsigned short* __restrict__ out)
{
    size_t i = ((size_t)blockIdx.x * 256 + threadIdx.x) * 8;
    float4 a = *(const float4*)(in + i);
    float4 b = *(const float4*)(in + i + 4);
    s8v o;
    o[0]=f2bf(a.x); o[1]=f2bf(a.y); o[2]=f2bf(a.z); o[3]=f2bf(a.w);
    o[4]=f2bf(b.x); o[5]=f2bf(b.y); o[6]=f2bf(b.z); o[7]=f2bf(b.w);
    *(s8v*)(out + i) = o;
}

// ---------------------------------------------------------------------------
// Convert W1, W2 -> bf16; W3 (50x512) -> bf16 padded to 64x512 (zero rows).
// ---------------------------------------------------------------------------
__global__ __launch_bounds__(256)
void convert_weights_kernel(const float* __restrict__ W1, const float* __restrict__ W2,
                            const float* __restrict__ W3,
                            unsigned short* __restrict__ W1b,
                            unsigned short* __restrict__ W2b,
                            unsigned short* __restrict__ W3b)
{
    int e = (blockIdx.x * 256 + threadIdx.x) * 8;
    if (e >= 524288) {                       // W3 padded region
        int off = e - 524288;
        int row = off >> 9;
        s8v o;
        #pragma unroll
        for (int j = 0; j < 8; ++j)
            o[j] = (row < Cc) ? (short)f2bf(W3[off + j]) : (short)0;
        *(s8v*)(W3b + off) = o;
        return;
    }
    const float* src = (e < 262144) ? W1 : W2;
    unsigned short* dst = (e < 262144) ? W1b : W2b;
    int off = (e < 262144) ? e : e - 262144;
    float4 a = *(const float4*)(src + off);
    float4 b = *(const float4*)(src + off + 4);
    s8v o;
    o[0]=f2bf(a.x); o[1]=f2bf(a.y); o[2]=f2bf(a.z); o[3]=f2bf(a.w);
    o[4]=f2bf(b.x); o[5]=f2bf(b.y); o[6]=f2bf(b.z); o[7]=f2bf(b.w);
    *(s8v*)(dst + off) = o;
}

// ---------------------------------------------------------------------------
// V (fp32, [b][l][h]) -> Vt (bf16, [b][h][l]).  64x64 LDS tile transpose.
// Vectorized write side: 4 x ushort4 stores per thread.  [round-3 form]
// ---------------------------------------------------------------------------
__global__ __launch_bounds__(256)
void transpose_v_kernel(const float* __restrict__ V, unsigned short* __restrict__ Vt)
{
    __shared__ float tile[64 * 65];
    const int l0 = blockIdx.x * 64;
    const int h0 = blockIdx.y * 64;
    const int b  = blockIdx.z;
    const int tid = threadIdx.x;
    const int li = tid >> 2;          // 0..63
    const int hq = (tid & 3) * 4;     // 0,4,8,12

    const float* src = V + ((size_t)(b * Lc + l0 + li)) * Hc + h0 + hq;
    #pragma unroll
    for (int j = 0; j < 4; ++j) {
        float4 v = *(const float4*)(src + 16 * j);
        float* d = &tile[li * 65 + hq + 16 * j];
        d[0] = v.x; d[1] = v.y; d[2] = v.z; d[3] = v.w;
    }
    __syncthreads();

    const int lane = tid & 63;
    const int w4   = tid >> 6;
    const int lpos = (lane & 15) * 4;          // 4 consecutive l per lane
    #pragma unroll
    for (int i = 0; i < 4; ++i) {
        int hr = i * 16 + w4 * 4 + (lane >> 4);   // 0..63, unique per (i,w4,hi)
        ushort4 o;
        o.x = f2bf(tile[(lpos + 0) * 65 + hr]);
        o.y = f2bf(tile[(lpos + 1) * 65 + hr]);
        o.z = f2bf(tile[(lpos + 2) * 65 + hr]);
        o.w = f2bf(tile[(lpos + 3) * 65 + hr]);
        *(ushort4*)(Vt + ((size_t)(b * Hc + h0 + hr)) * Lc + l0 + lpos) = o;
    }
}

// ---------------------------------------------------------------------------
// MFMA GEMM: Out = f(A @ W^T), 128x128 tile, BK=32.  [round-1 form, measured
// 81.7 us: plain __syncthreads K-loop (compiler schedules waits), XCD-grouped
// 1-D grid, vectorized LDS-transpose epilogue]
// mode 0: Out = bf16(fast_tanh(acc)); mode 1: Out = bf16(A[m,j]+fast_tanh(acc))
// ---------------------------------------------------------------------------
__global__ __launch_bounds__(256)
void mfma_gemm512(const unsigned short* __restrict__ Ab,
                  const unsigned short* __restrict__ Wb,
                  unsigned short* __restrict__ Ob, int mode)
{
    __shared__ alignas(16) unsigned short As[128 * 32];
    __shared__ alignas(16) unsigned short Bs[128 * 32];
    __shared__ alignas(16) float Esf[32 * 133];      // epilogue quarter-tile
    const int tid = threadIdx.x;
    const int w = tid >> 6, l = tid & 63;

    // XCD-grouped block mapping: grid = 2048 linear blocks.
    const int bid = blockIdx.x;
    const int ixd = bid >> 3;                 // 0..255 within XCD
    const int y   = (bid & 7) * 64 + (ixd >> 2);
    const int x   = ixd & 3;
    const int j0 = x * 128;
    const int i0 = y * 128;

    const int sr  = w * 16 + (l >> 2);
    const int kg8 = (l & 3) * 8;
    const unsigned short* Ag0 = Ab + (size_t)(i0 + sr) * 512 + kg8;
    const unsigned short* Ag1 = Ag0 + (size_t)64 * 512;
    const unsigned short* Bg0 = Wb + (size_t)(j0 + sr) * 512 + kg8;
    const unsigned short* Bg1 = Bg0 + (size_t)64 * 512;
    unsigned short* Al0 = As + w * 512;
    unsigned short* Al1 = As + 2048 + w * 512;
    unsigned short* Bl0 = Bs + w * 512;
    unsigned short* Bl1 = Bs + 2048 + w * 512;

    const int wm = (w & 1) * 64, wn = (w >> 1) * 64;
    const int fr = l & 15;
    const int fq = (l >> 4) * 8;

    f4v acc[4][4];
    #pragma unroll
    for (int r = 0; r < 4; ++r)
        #pragma unroll
        for (int c = 0; c < 4; ++c) acc[r][c] = (f4v){0.f, 0.f, 0.f, 0.f};

    for (int k0 = 0; k0 < 512; k0 += 32) {
        gl_lds16(Ag0 + k0, Al0);
        gl_lds16(Ag1 + k0, Al1);
        gl_lds16(Bg0 + k0, Bl0);
        gl_lds16(Bg1 + k0, Bl1);
        __syncthreads();
        s8v af[4], bf[4];
        #pragma unroll
        for (int r = 0; r < 4; ++r)
            af[r] = *(const s8v*)&As[(wm + r * 16 + fr) * 32 + fq];
        #pragma unroll
        for (int c = 0; c < 4; ++c)
            bf[c] = *(const s8v*)&Bs[(wn + c * 16 + fr) * 32 + fq];
        #pragma unroll
        for (int r = 0; r < 4; ++r)
            #pragma unroll
            for (int c = 0; c < 4; ++c)
                acc[r][c] = __builtin_amdgcn_mfma_f32_16x16x32_bf16(
                    af[r], bf[c], acc[r][c], 0, 0, 0);
        __syncthreads();
    }

    // Epilogue: 4 quarter-phases (32 rows each).
    #pragma unroll
    for (int h = 0; h < 4; ++h) {
        if (h) __syncthreads();              // previous phase's readers done
        if ((w & 1) == (h >> 1)) {
            const int rr = (h & 1) * 2;
            #pragma unroll
            for (int r = 0; r < 2; ++r)
                #pragma unroll
                for (int c = 0; c < 4; ++c)
                    #pragma unroll
                    for (int v = 0; v < 4; ++v) {
                        int row = r * 16 + (l >> 4) * 4 + v;   // 0..31
                        int col = wn + c * 16 + fr;            // 0..127
                        Esf[row * 133 + col] = fast_tanh(acc[rr + r][c][v]);
                    }
        }
        __syncthreads();
        #pragma unroll
        for (int t = 0; t < 4; ++t) {
            int chunk = t * 256 + tid;       // 0..1023
            int row = chunk >> 5;            // 0..31
            int c4  = (chunk & 31) * 4;      // 0..124
            f4v val = *(const f4v*)&Esf[row * 133 + c4];
            size_t gr   = (size_t)(i0 + (h >> 1) * 64 + (h & 1) * 32 + row);
            size_t goff = gr * 512 + j0 + c4;
            ushort4 o;
            if (mode) {
                ushort4 a = *(const ushort4*)(Ab + goff);
                o.x = f2bf(val[0] + bf2f(a.x));
                o.y = f2bf(val[1] + bf2f(a.y));
                o.z = f2bf(val[2] + bf2f(a.z));
                o.w = f2bf(val[3] + bf2f(a.w));
            } else {
                o.x = f2bf(val[0]); o.y = f2bf(val[1]);
                o.z = f2bf(val[2]); o.w = f2bf(val[3]);
            }
            *(ushort4*)(Ob + goff) = o;
        }
    }
}

// ---------------------------------------------------------------------------
// MFMA GEMM3: P3 = S @ W3^T (N=50 padded 64), fp32 out, row stride PCc=52.
// [round-3 form: 2-phase counted-vmcnt double-buffer, 3 loads -> vmcnt(3)]
// LDS 24 KB: [As0 8K][Bs0 4K][As1 8K][Bs1 4K].
// ---------------------------------------------------------------------------
__global__ __launch_bounds__(256)
void mfma_gemm_p3(const unsigned short* __restrict__ Sb,
                  const unsigned short* __restrict__ W3b,
                  float* __restrict__ P3)
{
    __shared__ alignas(16) char smem[24576];
    const int tid = threadIdx.x;
    const int w = tid >> 6, l = tid & 63;
    const int i0 = blockIdx.x * 128;

    const int sr  = w * 16 + (l >> 2);
    const int kg8 = (l & 3) * 8;
    const unsigned short* Ag0 = Sb + (size_t)(i0 + sr) * 512 + kg8;
    const unsigned short* Ag1 = Ag0 + (size_t)64 * 512;
    const unsigned short* Bg  = W3b + (size_t)sr * 512 + kg8;

    const int wm = w * 32;
    const int fr = l & 15;
    const int fq = (l >> 4) * 8;

    f4v acc[2][4];
    #pragma unroll
    for (int r = 0; r < 2; ++r)
        #pragma unroll
        for (int c = 0; c < 4; ++c) acc[r][c] = (f4v){0.f, 0.f, 0.f, 0.f};

    auto STAGE = [&](int buf, int k0) {
        unsigned short* a = (unsigned short*)(smem + buf * 12288);
        unsigned short* b = (unsigned short*)(smem + 8192 + buf * 12288);
        gl_lds16(Ag0 + k0, a + w * 512);
        gl_lds16(Ag1 + k0, a + 2048 + w * 512);
        gl_lds16(Bg  + k0, b + w * 512);
    };
    auto COMPUTE = [&](int buf) {
        const unsigned short* a = (const unsigned short*)(smem + buf * 12288);
        const unsigned short* b = (const unsigned short*)(smem + 8192 + buf * 12288);
        s8v af[2], bv[4];
        #pragma unroll
        for (int r = 0; r < 2; ++r)
            af[r] = *(const s8v*)&a[(wm + r * 16 + fr) * 32 + fq];
        #pragma unroll
        for (int c = 0; c < 4; ++c)
            bv[c] = *(const s8v*)&b[(c * 16 + fr) * 32 + fq];
        #pragma unroll
        for (int r = 0; r < 2; ++r)
            #pragma unroll
            for (int c = 0; c < 4; ++c)
                acc[r][c] = __builtin_amdgcn_mfma_f32_16x16x32_bf16(
                    af[r], bv[c], acc[r][c], 0, 0, 0);
    };

    STAGE(0, 0);
    #pragma unroll
    for (int t = 0; t < 15; ++t) {
        STAGE((t + 1) & 1, (t + 1) * 32);
        asm volatile("s_waitcnt vmcnt(3)" ::: "memory");
        __builtin_amdgcn_s_barrier();
        COMPUTE(t & 1);
        asm volatile("s_waitcnt lgkmcnt(0)" ::: "memory");
        __builtin_amdgcn_s_barrier();
    }
    asm volatile("s_waitcnt vmcnt(0)" ::: "memory");
    __builtin_amdgcn_s_barrier();
    COMPUTE(1);

    #pragma unroll
    for (int r = 0; r < 2; ++r)
        #pragma unroll
        for (int v = 0; v < 4; ++v) {
            const int row = i0 + wm + r * 16 + (l >> 4) * 4 + v;
            #pragma unroll
            for (int c = 0; c < 4; ++c) {
                const int col = c * 16 + fr;
                if (col < Cc) P3[(size_t)row * PCc + col] = acc[r][c][v];
            }
        }
}

// ---------------------------------------------------------------------------
// sent_lens dtype hedge (int64 vs int32 auto-detect).
// ---------------------------------------------------------------------------
__global__ __launch_bounds__(64)
void normalize_lens_kernel(const int* __restrict__ raw, int* __restrict__ lens)
{
    __shared__ int is64;
    if (threadIdx.x == 0) {
        int orv = 0;
        for (int i = 1; i < 32; i += 2) orv |= raw[i];
        is64 = (orv == 0) ? 1 : 0;
    }
    __syncthreads();
    int b = threadIdx.x;
    if (b < Bc) lens[b] = is64 ? raw[2*b] : raw[b];
}

// ---------------------------------------------------------------------------
// kq-fill + avgpool3(count_include_pad=False) + softmax + mask.
// ---------------------------------------------------------------------------
__global__ __launch_bounds__(256)
void pool_softmax_kernel(const float* __restrict__ P3, const int* __restrict__ lens,
                         float* __restrict__ out_attn, float* __restrict__ out_smooth,
                         unsigned short* __restrict__ attnT)
{
    const int idx = blockIdx.x * 256 + threadIdx.x;   // b*L + l
    const int b = idx >> 11;
    const int l = idx & (Lc - 1);
    const int len = lens[b];
    const float* base = P3 + (size_t)b * Lc * PCc;

    const int  r0 = min(l, len - 1);
    const bool hm = (l > 0);
    const bool hp = (l < Lc - 1);
    const int  rm = hm ? min(l - 1, len - 1) : 0;
    const int  rp = hp ? min(l + 1, len - 1) : 0;
    const float rcnt = 1.f / (1.f + (hm ? 1.f : 0.f) + (hp ? 1.f : 0.f));

    float sm[PCc];
    const float* p0 = base + (size_t)r0 * PCc;
    #pragma unroll
    for (int q = 0; q < 13; ++q) {
        f4v v = *(const f4v*)(p0 + q * 4);
        sm[q*4+0] = v[0]; sm[q*4+1] = v[1]; sm[q*4+2] = v[2]; sm[q*4+3] = v[3];
    }
    if (hm) {
        const float* p = base + (size_t)rm * PCc;
        #pragma unroll
        for (int q = 0; q < 13; ++q) {
            f4v v = *(const f4v*)(p + q * 4);
            sm[q*4+0] += v[0]; sm[q*4+1] += v[1]; sm[q*4+2] += v[2]; sm[q*4+3] += v[3];
        }
    }
    if (hp) {
        const float* p = base + (size_t)rp * PCc;
        #pragma unroll
        for (int q = 0; q < 13; ++q) {
            f4v v = *(const f4v*)(p + q * 4);
            sm[q*4+0] += v[0]; sm[q*4+1] += v[1]; sm[q*4+2] += v[2]; sm[q*4+3] += v[3];
        }
    }

    float mx = -1e30f;
    #pragma unroll
    for (int c = 0; c < Cc; ++c) {
        sm[c] *= rcnt;
        mx = fmaxf(mx, sm[c]);
    }
    float* srow = out_smooth + (size_t)idx * Cc;
    #pragma unroll
    for (int q = 0; q < 25; ++q) {
        float2 v = make_float2(sm[q*2], sm[q*2+1]);
        *(float2*)(srow + q * 2) = v;
    }

    float sum = 0.f;
    #pragma unroll
    for (int c = 0; c < Cc; ++c) {
        float e = __expf(sm[c] - mx);
        sm[c] = e;
        sum += e;
    }
    const float inv = 1.f / sum;
    const bool valid = (l < len);
    const float scale = valid ? inv : 0.f;
    float* arow = out_attn + (size_t)idx * Cc;
    unsigned short* trow = attnT + (size_t)b * 64 * Lc + l;
    #pragma unroll
    for (int c = 0; c < Cc; ++c) sm[c] *= scale;
    #pragma unroll
    for (int q = 0; q < 25; ++q)
        *(float2*)(arow + q * 2) = make_float2(sm[q*2], sm[q*2+1]);
    #pragma unroll
    for (int c = 0; c < Cc; ++c)
        trow[(size_t)c * Lc] = f2bf(sm[c]);
}

// ---------------------------------------------------------------------------
// class_inputs[b,c,h] = sum_l attn[b,l,c] * V[b,l,h]  -- MFMA.
// [round-3 form: XCD-grouped linear grid (512 blocks), plain BK=32 loop]
// ---------------------------------------------------------------------------
__global__ __launch_bounds__(256)
void class_mfma_kernel(const unsigned short* __restrict__ attnT,
                       const unsigned short* __restrict__ Vt,
                       float* __restrict__ out_class)
{
    __shared__ alignas(16) unsigned short As[64 * 32];    // 4 KB
    __shared__ alignas(16) unsigned short Bs[128 * 32];   // 8 KB
    const int tid = threadIdx.x;
    const int w = tid >> 6, l = tid & 63;

    const int bid  = blockIdx.x;              // 0..511
    const int ixd  = bid >> 3;                // 0..63 within XCD
    const int pair = (bid & 7) * 16 + (ixd >> 2);   // 0..127 = (b,z)
    const int n0 = (ixd & 3) * 128;
    const int b  = pair >> 2;
    const int kb = (pair & 3) * 512;

    const int sr  = w * 16 + (l >> 2);   // 0..63
    const int kg8 = (l & 3) * 8;
    const unsigned short* Ag  = attnT + ((size_t)b * 64 + sr) * Lc + kg8;
    const unsigned short* Bg0 = Vt + ((size_t)(b * Hc + n0 + sr)) * Lc + kg8;
    const unsigned short* Bg1 = Bg0 + (size_t)64 * Lc;
    unsigned short* Al  = As + w * 512;
    unsigned short* Bl0 = Bs + w * 512;
    unsigned short* Bl1 = Bs + 2048 + w * 512;

    const int fr = l & 15;
    const int fq = (l >> 4) * 8;

    f4v acc[4][2];
    #pragma unroll
    for (int r = 0; r < 4; ++r)
        #pragma unroll
        for (int c = 0; c < 2; ++c) acc[r][c] = (f4v){0.f, 0.f, 0.f, 0.f};

    for (int k0 = kb; k0 < kb + 512; k0 += 32) {
        gl_lds16(Ag + k0, Al);
        gl_lds16(Bg0 + k0, Bl0);
        gl_lds16(Bg1 + k0, Bl1);
        __syncthreads();
        s8v af[4], bv[2];
        #pragma unroll
        for (int r = 0; r < 4; ++r)
            af[r] = *(const s8v*)&As[(r * 16 + fr) * 32 + fq];
        #pragma unroll
        for (int c = 0; c < 2; ++c)
            bv[c] = *(const s8v*)&Bs[(w * 32 + c * 16 + fr) * 32 + fq];
        #pragma unroll
        for (int r = 0; r < 4; ++r)
            #pragma unroll
            for (int c = 0; c < 2; ++c)
                acc[r][c] = __builtin_amdgcn_mfma_f32_16x16x32_bf16(
                    af[r], bv[c], acc[r][c], 0, 0, 0);
        __syncthreads();
    }

    #pragma unroll
    for (int r = 0; r < 4; ++r)
        #pragma unroll
        for (int v = 0; v < 4; ++v) {
            const int m = r * 16 + (l >> 4) * 4 + v;   // class index
            if (m < Cc) {
                #pragma unroll
                for (int c = 0; c < 2; ++c) {
                    const int h = n0 + w * 32 + c * 16 + fr;
                    atomicAdd(out_class + ((size_t)b * Cc + m) * Hc + h,
                              acc[r][c][v]);
                }
            }
        }
}

// ---------------------------------------------------------------------------
// Workspace layout (~203 MiB, overlays exploit stream ordering):
//   off 0      : Akv bf16 (64 MiB)      -> later P3 fp32 stride-52 (13.6 MiB)
//   off 64 MiB : P1b bf16 (64 MiB)      -> later Vt bf16 (64 MiB)
//   off 128 MiB: Sb  bf16 (64 MiB)
//   off 192 MiB: W1b, W2b (0.5 MiB each), W3b (64 KiB)
//   off 194 MiB: attnT bf16 32x64x2048 (8 MiB)
//   off 202 MiB: lens (128 B)
// ---------------------------------------------------------------------------
extern "C" void kernel_launch(void* const* d_in, const int* in_sizes, int n_in,
                              void* d_out, int out_size, void* d_ws, size_t ws_size,
                              hipStream_t stream)
{
    const float* keys     = (const float*)d_in[0];
    const float* vals     = (const float*)d_in[1];
    const int*   lens_raw = (const int*)d_in[2];
    const float* W1       = (const float*)d_in[3];
    const float* W2       = (const float*)d_in[4];
    const float* W3       = (const float*)d_in[5];

    char* ws = (char*)d_ws;
    const size_t MB = 1024 * 1024;
    unsigned short* Akv  = (unsigned short*)ws;
    float*          P3   = (float*)ws;                       // over Akv (dead)
    unsigned short* P1b  = (unsigned short*)(ws + 64 * MB);
    unsigned short* Vt   = (unsigned short*)(ws + 64 * MB);  // over P1b (dead)
    unsigned short* Sb   = (unsigned short*)(ws + 128 * MB);
    unsigned short* W1b  = (unsigned short*)(ws + 192 * MB);
    unsigned short* W2b  = W1b + Hc * Hc;
    unsigned short* W3b  = W2b + Hc * Hc;
    unsigned short* attnT= (unsigned short*)(ws + 194 * MB);
    int*            lens = (int*)(ws + 202 * MB);

    float* out_attn   = (float*)d_out;
    float* out_class  = out_attn + (size_t)Bc * Lc * Cc;
    float* out_smooth = out_class + (size_t)Bc * Cc * Hc;

    hipMemsetAsync(out_class, 0, (size_t)Bc * Cc * Hc * sizeof(float), stream);

    f32_to_bf16_kernel<<<(Mc * Hc / 8) / 256, 256, 0, stream>>>(keys, Akv);
    convert_weights_kernel<<<272, 256, 0, stream>>>(W1, W2, W3, W1b, W2b, W3b);
    normalize_lens_kernel<<<1, 64, 0, stream>>>(lens_raw, lens);

    // P1 = tanh(keys @ W1^T)   [bf16 out]
    mfma_gemm512<<<2048, 256, 0, stream>>>(Akv, W1b, P1b, 0);
    // S = P1 + tanh(P1 @ W2^T) [bf16 out]
    mfma_gemm512<<<2048, 256, 0, stream>>>(P1b, W2b, Sb, 1);
    // Vt = transpose(bf16(vals))  (P1b dead now; Vt overlays it)
    transpose_v_kernel<<<dim3(Lc / 64, Hc / 64, Bc), 256, 0, stream>>>(vals, Vt);
    // P3 = S @ W3^T            [fp32 out, stride 52, overlays dead Akv]
    mfma_gemm_p3<<<Mc / 128, 256, 0, stream>>>(Sb, W3b, P3);
    // pool + softmax + mask; also emits attnT bf16
    pool_softmax_kernel<<<Mc / 256, 256, 0, stream>>>(P3, lens, out_attn, out_smooth, attnT);
    // class_inputs = attnT @ Vt^T per batch (MFMA, K-split 4, atomic reduce)
    class_mfma_kernel<<<512, 256, 0, stream>>>(attnT, Vt, out_class);
}

// Round 6
// 477.503 us; speedup vs baseline: 1.0846x; 1.0443x over previous
//
#include <hip/hip_runtime.h>
#include <cstdint>

// Problem constants
#define Bc 32
#define Lc 2048
#define Hc 512
#define Cc 50
#define PCc 52        // P3 row stride (52 floats = 208 B, 16B-aligned)
#define Mc (Bc*Lc)    // 65536 rows

typedef short s8v   __attribute__((ext_vector_type(8)));   // 8 bf16 (4 VGPRs)
typedef float f4v   __attribute__((ext_vector_type(4)));   // MFMA C/D

__device__ inline unsigned short f2bf(float f) {            // RNE fp32->bf16
    unsigned int u = __float_as_uint(f);
    u += 0x7fffu + ((u >> 16) & 1u);
    return (unsigned short)(u >> 16);
}
__device__ inline float bf2f(unsigned short h) {
    return __uint_as_float(((unsigned int)h) << 16);
}
// tanh(x) = 1 - 2/(e^{2x}+1): ~5 VALU ops (mul, v_exp, add, rcp, fma).
__device__ inline float fast_tanh(float x) {
    float e = __expf(2.0f * x);
    return 1.0f - 2.0f / (e + 1.0f);
}
__device__ inline void gl_lds16(const unsigned short* g, unsigned short* l) {
    __builtin_amdgcn_global_load_lds(
        (const __attribute__((address_space(1))) unsigned int*)g,
        (__attribute__((address_space(3))) unsigned int*)l, 16, 0, 0);
}

// ---------------------------------------------------------------------------
// fp32 -> bf16 bulk convert (keys). 8 elements/thread.
// ---------------------------------------------------------------------------
__global__ __launch_bounds__(256)
void f32_to_bf16_kernel(const float* __restrict__ in, unsigned short* __restrict__ out)
{
    size_t i = ((size_t)blockIdx.x * 256 + threadIdx.x) * 8;
    float4 a = *(const float4*)(in + i);
    float4 b = *(const float4*)(in + i + 4);
    s8v o;
    o[0]=f2bf(a.x); o[1]=f2bf(a.y); o[2]=f2bf(a.z); o[3]=f2bf(a.w);
    o[4]=f2bf(b.x); o[5]=f2bf(b.y); o[6]=f2bf(b.z); o[7]=f2bf(b.w);
    *(s8v*)(out + i) = o;
}

// ---------------------------------------------------------------------------
// Convert W1, W2 -> bf16; W3 (50x512) -> bf16 padded to 64x512 (zero rows).
// ---------------------------------------------------------------------------
__global__ __launch_bounds__(256)
void convert_weights_kernel(const float* __restrict__ W1, const float* __restrict__ W2,
                            const float* __restrict__ W3,
                            unsigned short* __restrict__ W1b,
                            unsigned short* __restrict__ W2b,
                            unsigned short* __restrict__ W3b)
{
    int e = (blockIdx.x * 256 + threadIdx.x) * 8;
    if (e >= 524288) {                       // W3 padded region
        int off = e - 524288;
        int row = off >> 9;
        s8v o;
        #pragma unroll
        for (int j = 0; j < 8; ++j)
            o[j] = (row < Cc) ? (short)f2bf(W3[off + j]) : (short)0;
        *(s8v*)(W3b + off) = o;
        return;
    }
    const float* src = (e < 262144) ? W1 : W2;
    unsigned short* dst = (e < 262144) ? W1b : W2b;
    int off = (e < 262144) ? e : e - 262144;
    float4 a = *(const float4*)(src + off);
    float4 b = *(const float4*)(src + off + 4);
    s8v o;
    o[0]=f2bf(a.x); o[1]=f2bf(a.y); o[2]=f2bf(a.z); o[3]=f2bf(a.w);
    o[4]=f2bf(b.x); o[5]=f2bf(b.y); o[6]=f2bf(b.z); o[7]=f2bf(b.w);
    *(s8v*)(dst + off) = o;
}

// ---------------------------------------------------------------------------
// V (fp32, [b][l][h]) -> Vt (bf16, [b][h][l]).  64x64 LDS tile transpose.
// ---------------------------------------------------------------------------
__global__ __launch_bounds__(256)
void transpose_v_kernel(const float* __restrict__ V, unsigned short* __restrict__ Vt)
{
    __shared__ float tile[64 * 65];
    const int l0 = blockIdx.x * 64;
    const int h0 = blockIdx.y * 64;
    const int b  = blockIdx.z;
    const int tid = threadIdx.x;
    const int li = tid >> 2;          // 0..63
    const int hq = (tid & 3) * 4;     // 0,4,8,12

    const float* src = V + ((size_t)(b * Lc + l0 + li)) * Hc + h0 + hq;
    #pragma unroll
    for (int j = 0; j < 4; ++j) {
        float4 v = *(const float4*)(src + 16 * j);
        float* d = &tile[li * 65 + hq + 16 * j];
        d[0] = v.x; d[1] = v.y; d[2] = v.z; d[3] = v.w;
    }
    __syncthreads();

    const int lane = tid & 63;
    const int w4   = tid >> 6;
    const int lpos = (lane & 15) * 4;          // 4 consecutive l per lane
    #pragma unroll
    for (int i = 0; i < 4; ++i) {
        int hr = i * 16 + w4 * 4 + (lane >> 4);   // 0..63, unique per (i,w4,hi)
        ushort4 o;
        o.x = f2bf(tile[(lpos + 0) * 65 + hr]);
        o.y = f2bf(tile[(lpos + 1) * 65 + hr]);
        o.z = f2bf(tile[(lpos + 2) * 65 + hr]);
        o.w = f2bf(tile[(lpos + 3) * 65 + hr]);
        *(ushort4*)(Vt + ((size_t)(b * Hc + h0 + hr)) * Lc + l0 + lpos) = o;
    }
}

// ---------------------------------------------------------------------------
// MFMA GEMM1: P1 = bf16(fast_tanh(keys @ W1^T)), 128x128 tile, BK=32.
// [round-1 form, measured 81.7 us — unchanged]
// ---------------------------------------------------------------------------
__global__ __launch_bounds__(256)
void mfma_gemm512(const unsigned short* __restrict__ Ab,
                  const unsigned short* __restrict__ Wb,
                  unsigned short* __restrict__ Ob)
{
    __shared__ alignas(16) unsigned short As[128 * 32];
    __shared__ alignas(16) unsigned short Bs[128 * 32];
    __shared__ alignas(16) float Esf[32 * 133];      // epilogue quarter-tile
    const int tid = threadIdx.x;
    const int w = tid >> 6, l = tid & 63;

    const int bid = blockIdx.x;
    const int ixd = bid >> 3;                 // 0..255 within XCD
    const int y   = (bid & 7) * 64 + (ixd >> 2);
    const int x   = ixd & 3;
    const int j0 = x * 128;
    const int i0 = y * 128;

    const int sr  = w * 16 + (l >> 2);
    const int kg8 = (l & 3) * 8;
    const unsigned short* Ag0 = Ab + (size_t)(i0 + sr) * 512 + kg8;
    const unsigned short* Ag1 = Ag0 + (size_t)64 * 512;
    const unsigned short* Bg0 = Wb + (size_t)(j0 + sr) * 512 + kg8;
    const unsigned short* Bg1 = Bg0 + (size_t)64 * 512;
    unsigned short* Al0 = As + w * 512;
    unsigned short* Al1 = As + 2048 + w * 512;
    unsigned short* Bl0 = Bs + w * 512;
    unsigned short* Bl1 = Bs + 2048 + w * 512;

    const int wm = (w & 1) * 64, wn = (w >> 1) * 64;
    const int fr = l & 15;
    const int fq = (l >> 4) * 8;

    f4v acc[4][4];
    #pragma unroll
    for (int r = 0; r < 4; ++r)
        #pragma unroll
        for (int c = 0; c < 4; ++c) acc[r][c] = (f4v){0.f, 0.f, 0.f, 0.f};

    for (int k0 = 0; k0 < 512; k0 += 32) {
        gl_lds16(Ag0 + k0, Al0);
        gl_lds16(Ag1 + k0, Al1);
        gl_lds16(Bg0 + k0, Bl0);
        gl_lds16(Bg1 + k0, Bl1);
        __syncthreads();
        s8v af[4], bf[4];
        #pragma unroll
        for (int r = 0; r < 4; ++r)
            af[r] = *(const s8v*)&As[(wm + r * 16 + fr) * 32 + fq];
        #pragma unroll
        for (int c = 0; c < 4; ++c)
            bf[c] = *(const s8v*)&Bs[(wn + c * 16 + fr) * 32 + fq];
        #pragma unroll
        for (int r = 0; r < 4; ++r)
            #pragma unroll
            for (int c = 0; c < 4; ++c)
                acc[r][c] = __builtin_amdgcn_mfma_f32_16x16x32_bf16(
                    af[r], bf[c], acc[r][c], 0, 0, 0);
        __syncthreads();
    }

    #pragma unroll
    for (int h = 0; h < 4; ++h) {
        if (h) __syncthreads();
        if ((w & 1) == (h >> 1)) {
            const int rr = (h & 1) * 2;
            #pragma unroll
            for (int r = 0; r < 2; ++r)
                #pragma unroll
                for (int c = 0; c < 4; ++c)
                    #pragma unroll
                    for (int v = 0; v < 4; ++v) {
                        int row = r * 16 + (l >> 4) * 4 + v;   // 0..31
                        int col = wn + c * 16 + fr;            // 0..127
                        Esf[row * 133 + col] = fast_tanh(acc[rr + r][c][v]);
                    }
        }
        __syncthreads();
        #pragma unroll
        for (int t = 0; t < 4; ++t) {
            int chunk = t * 256 + tid;       // 0..1023
            int row = chunk >> 5;            // 0..31
            int c4  = (chunk & 31) * 4;      // 0..124
            f4v val = *(const f4v*)&Esf[row * 133 + c4];
            size_t gr   = (size_t)(i0 + (h >> 1) * 64 + (h & 1) * 32 + row);
            size_t goff = gr * 512 + j0 + c4;
            ushort4 o;
            o.x = f2bf(val[0]); o.y = f2bf(val[1]);
            o.z = f2bf(val[2]); o.w = f2bf(val[3]);
            *(ushort4*)(Ob + goff) = o;
        }
    }
}

// ---------------------------------------------------------------------------
// FUSED GEMM2+GEMM3 (no atomics): block owns rows i0..i0+64 x ALL 512 cols.
//   S_tile = P1 + tanh(P1 @ W2^T)  built in LDS (bf16, [64][520])
//   P3[i0:i0+64, 0:50] = S_tile @ W3^T   -- contraction over n is block-LOCAL
//                                           -> plain stores, no split-K.
// Numerics identical to the verified chain: single bf16 rounding of
// (fp32 tanh + bf16 P1), via pass order:
//   pass1: copy P1 tile (bf16, no rounding) into Ss  [vectorized s8v]
//   pass2: Ss = f2bf(bf2f(Ss) + fast_tanh(acc))      [scalar LDS RMW]
//   pass3: GEMM3 from Ss fragments + L1-resident W3, direct P3 stores.
// K-loop: proven BK=32 chunked staging ([row][32] 64B rows, gl_lds16-legal),
// plain __syncthreads. 512 threads, LDS 66560 B -> 2 blocks/CU (16 waves/CU).
// ---------------------------------------------------------------------------
__global__ __launch_bounds__(512, 4)
void mfma_gemm2_fused(const unsigned short* __restrict__ Ab,   // P1b
                      const unsigned short* __restrict__ Wb,   // W2b
                      const unsigned short* __restrict__ W3g,  // W3b (64x512)
                      float* __restrict__ P3)
{
    __shared__ alignas(16) char smem[66560];
    unsigned short* Ast = (unsigned short*)smem;            // [64*32]  4 KB (K-loop)
    unsigned short* Bst = (unsigned short*)(smem + 4096);   // [512*32] 32 KB (K-loop)
    unsigned short* Ss  = (unsigned short*)smem;            // [64][520] 66.5 KB (epilogue)

    const int tid = threadIdx.x;
    const int w = tid >> 6, l = tid & 63;     // 8 waves
    const int i0 = blockIdx.x * 64;

    const int sr  = tid >> 2;                 // 0..127
    const int kg8 = (tid & 3) * 8;
    const int fr  = l & 15;
    const int fq  = (l >> 4) * 8;
    const int wn  = w * 64;                   // wave's 64-col slice of N=512

    const unsigned short* AgP = Ab + (size_t)(i0 + sr) * 512 + kg8;  // sr<64 only
    const unsigned short* BgP = Wb + (size_t)sr * 512 + kg8;

    f4v acc[4][4];
    #pragma unroll
    for (int r = 0; r < 4; ++r)
        #pragma unroll
        for (int c = 0; c < 4; ++c) acc[r][c] = (f4v){0.f, 0.f, 0.f, 0.f};

    for (int k0 = 0; k0 < 512; k0 += 32) {
        if (tid < 256)                                        // waves 0-3: A tile
            gl_lds16(AgP + k0, Ast + sr * 32 + kg8);
        #pragma unroll
        for (int rr = 0; rr < 4; ++rr)                        // all: W2 512x32
            gl_lds16(BgP + (size_t)rr * 128 * 512 + k0,
                     Bst + (rr * 128 + sr) * 32 + kg8);
        __syncthreads();
        s8v af[4], bv[4];
        #pragma unroll
        for (int r = 0; r < 4; ++r)                           // A rows 0..63 (shared)
            af[r] = *(const s8v*)&Ast[(r * 16 + fr) * 32 + fq];
        #pragma unroll
        for (int c = 0; c < 4; ++c)                           // B rows wn..wn+63
            bv[c] = *(const s8v*)&Bst[(wn + c * 16 + fr) * 32 + fq];
        #pragma unroll
        for (int r = 0; r < 4; ++r)
            #pragma unroll
            for (int c = 0; c < 4; ++c)
                acc[r][c] = __builtin_amdgcn_mfma_f32_16x16x32_bf16(
                    af[r], bv[c], acc[r][c], 0, 0, 0);
        __syncthreads();
    }

    // ---- pass1: P1 tile -> Ss (vectorized copy, overlays dead staging) ----
    {
        const int row = tid >> 3;          // 0..63
        const int c0  = (tid & 7) * 8;     // 0,8,..,56
        #pragma unroll
        for (int q = 0; q < 8; ++q) {
            int col = c0 + q * 64;
            *(s8v*)&Ss[row * 520 + col] =
                *(const s8v*)(Ab + (size_t)(i0 + row) * 512 + col);
        }
    }
    __syncthreads();

    // ---- pass2: Ss = bf16( P1 + tanh(acc) )  (single rounding) ----
    #pragma unroll
    for (int r = 0; r < 4; ++r)
        #pragma unroll
        for (int c = 0; c < 4; ++c)
            #pragma unroll
            for (int v = 0; v < 4; ++v) {
                int row = r * 16 + (l >> 4) * 4 + v;          // 0..63
                int col = wn + c * 16 + fr;                   // 0..511
                unsigned short* p = &Ss[row * 520 + col];
                *p = f2bf(bf2f(*p) + fast_tanh(acc[r][c][v]));
            }
    __syncthreads();

    // ---- pass3: P3 = Ss @ W3^T (local contraction over n=512) ----
    const int cb = (w & 3) * 16;           // class col-block
    const int rh = (w >> 2) * 32;          // row half
    f4v acc3[2];
    acc3[0] = (f4v){0.f, 0.f, 0.f, 0.f};
    acc3[1] = (f4v){0.f, 0.f, 0.f, 0.f};
    #pragma unroll
    for (int ks = 0; ks < 16; ++ks) {
        s8v bv3 = *(const s8v*)(W3g + (size_t)(cb + fr) * 512 + ks * 32 + fq);
        #pragma unroll
        for (int r = 0; r < 2; ++r) {
            s8v av = *(const s8v*)&Ss[(rh + r * 16 + fr) * 520 + ks * 32 + fq];
            acc3[r] = __builtin_amdgcn_mfma_f32_16x16x32_bf16(
                av, bv3, acc3[r], 0, 0, 0);
        }
    }
    #pragma unroll
    for (int r = 0; r < 2; ++r)
        #pragma unroll
        for (int v = 0; v < 4; ++v) {
            const int row = i0 + rh + r * 16 + (l >> 4) * 4 + v;
            const int cls = cb + fr;
            if (cls < Cc) P3[(size_t)row * PCc + cls] = acc3[r][v];
        }
}

// ---------------------------------------------------------------------------
// sent_lens dtype hedge (int64 vs int32 auto-detect).
// ---------------------------------------------------------------------------
__global__ __launch_bounds__(64)
void normalize_lens_kernel(const int* __restrict__ raw, int* __restrict__ lens)
{
    __shared__ int is64;
    if (threadIdx.x == 0) {
        int orv = 0;
        for (int i = 1; i < 32; i += 2) orv |= raw[i];
        is64 = (orv == 0) ? 1 : 0;
    }
    __syncthreads();
    int b = threadIdx.x;
    if (b < Bc) lens[b] = is64 ? raw[2*b] : raw[b];
}

// ---------------------------------------------------------------------------
// kq-fill + avgpool3(count_include_pad=False) + softmax + mask.
// ---------------------------------------------------------------------------
__global__ __launch_bounds__(256)
void pool_softmax_kernel(const float* __restrict__ P3, const int* __restrict__ lens,
                         float* __restrict__ out_attn, float* __restrict__ out_smooth,
                         unsigned short* __restrict__ attnT)
{
    const int idx = blockIdx.x * 256 + threadIdx.x;   // b*L + l
    const int b = idx >> 11;
    const int l = idx & (Lc - 1);
    const int len = lens[b];
    const float* base = P3 + (size_t)b * Lc * PCc;

    const int  r0 = min(l, len - 1);
    const bool hm = (l > 0);
    const bool hp = (l < Lc - 1);
    const int  rm = hm ? min(l - 1, len - 1) : 0;
    const int  rp = hp ? min(l + 1, len - 1) : 0;
    const float rcnt = 1.f / (1.f + (hm ? 1.f : 0.f) + (hp ? 1.f : 0.f));

    float sm[PCc];
    const float* p0 = base + (size_t)r0 * PCc;
    #pragma unroll
    for (int q = 0; q < 13; ++q) {
        f4v v = *(const f4v*)(p0 + q * 4);
        sm[q*4+0] = v[0]; sm[q*4+1] = v[1]; sm[q*4+2] = v[2]; sm[q*4+3] = v[3];
    }
    if (hm) {
        const float* p = base + (size_t)rm * PCc;
        #pragma unroll
        for (int q = 0; q < 13; ++q) {
            f4v v = *(const f4v*)(p + q * 4);
            sm[q*4+0] += v[0]; sm[q*4+1] += v[1]; sm[q*4+2] += v[2]; sm[q*4+3] += v[3];
        }
    }
    if (hp) {
        const float* p = base + (size_t)rp * PCc;
        #pragma unroll
        for (int q = 0; q < 13; ++q) {
            f4v v = *(const f4v*)(p + q * 4);
            sm[q*4+0] += v[0]; sm[q*4+1] += v[1]; sm[q*4+2] += v[2]; sm[q*4+3] += v[3];
        }
    }

    float mx = -1e30f;
    #pragma unroll
    for (int c = 0; c < Cc; ++c) {
        sm[c] *= rcnt;
        mx = fmaxf(mx, sm[c]);
    }
    float* srow = out_smooth + (size_t)idx * Cc;
    #pragma unroll
    for (int q = 0; q < 25; ++q) {
        float2 v = make_float2(sm[q*2], sm[q*2+1]);
        *(float2*)(srow + q * 2) = v;
    }

    float sum = 0.f;
    #pragma unroll
    for (int c = 0; c < Cc; ++c) {
        float e = __expf(sm[c] - mx);
        sm[c] = e;
        sum += e;
    }
    const float inv = 1.f / sum;
    const bool valid = (l < len);
    const float scale = valid ? inv : 0.f;
    float* arow = out_attn + (size_t)idx * Cc;
    unsigned short* trow = attnT + (size_t)b * 64 * Lc + l;
    #pragma unroll
    for (int c = 0; c < Cc; ++c) sm[c] *= scale;
    #pragma unroll
    for (int q = 0; q < 25; ++q)
        *(float2*)(arow + q * 2) = make_float2(sm[q*2], sm[q*2+1]);
    #pragma unroll
    for (int c = 0; c < Cc; ++c)
        trow[(size_t)c * Lc] = f2bf(sm[c]);
}

// ---------------------------------------------------------------------------
// class_inputs[b,c,h] = sum_l attn[b,l,c] * V[b,l,h]  -- MFMA.
// [XCD-grouped linear grid (512 blocks), plain BK=32 loop — unchanged]
// ---------------------------------------------------------------------------
__global__ __launch_bounds__(256)
void class_mfma_kernel(const unsigned short* __restrict__ attnT,
                       const unsigned short* __restrict__ Vt,
                       float* __restrict__ out_class)
{
    __shared__ alignas(16) unsigned short As[64 * 32];    // 4 KB
    __shared__ alignas(16) unsigned short Bs[128 * 32];   // 8 KB
    const int tid = threadIdx.x;
    const int w = tid >> 6, l = tid & 63;

    const int bid  = blockIdx.x;              // 0..511
    const int ixd  = bid >> 3;                // 0..63 within XCD
    const int pair = (bid & 7) * 16 + (ixd >> 2);   // 0..127 = (b,z)
    const int n0 = (ixd & 3) * 128;
    const int b  = pair >> 2;
    const int kb = (pair & 3) * 512;

    const int sr  = w * 16 + (l >> 2);   // 0..63
    const int kg8 = (l & 3) * 8;
    const unsigned short* Ag  = attnT + ((size_t)b * 64 + sr) * Lc + kg8;
    const unsigned short* Bg0 = Vt + ((size_t)(b * Hc + n0 + sr)) * Lc + kg8;
    const unsigned short* Bg1 = Bg0 + (size_t)64 * Lc;
    unsigned short* Al  = As + w * 512;
    unsigned short* Bl0 = Bs + w * 512;
    unsigned short* Bl1 = Bs + 2048 + w * 512;

    const int fr = l & 15;
    const int fq = (l >> 4) * 8;

    f4v acc[4][2];
    #pragma unroll
    for (int r = 0; r < 4; ++r)
        #pragma unroll
        for (int c = 0; c < 2; ++c) acc[r][c] = (f4v){0.f, 0.f, 0.f, 0.f};

    for (int k0 = kb; k0 < kb + 512; k0 += 32) {
        gl_lds16(Ag + k0, Al);
        gl_lds16(Bg0 + k0, Bl0);
        gl_lds16(Bg1 + k0, Bl1);
        __syncthreads();
        s8v af[4], bv[2];
        #pragma unroll
        for (int r = 0; r < 4; ++r)
            af[r] = *(const s8v*)&As[(r * 16 + fr) * 32 + fq];
        #pragma unroll
        for (int c = 0; c < 2; ++c)
            bv[c] = *(const s8v*)&Bs[(w * 32 + c * 16 + fr) * 32 + fq];
        #pragma unroll
        for (int r = 0; r < 4; ++r)
            #pragma unroll
            for (int c = 0; c < 2; ++c)
                acc[r][c] = __builtin_amdgcn_mfma_f32_16x16x32_bf16(
                    af[r], bv[c], acc[r][c], 0, 0, 0);
        __syncthreads();
    }

    #pragma unroll
    for (int r = 0; r < 4; ++r)
        #pragma unroll
        for (int v = 0; v < 4; ++v) {
            const int m = r * 16 + (l >> 4) * 4 + v;   // class index
            if (m < Cc) {
                #pragma unroll
                for (int c = 0; c < 2; ++c) {
                    const int h = n0 + w * 32 + c * 16 + fr;
                    atomicAdd(out_class + ((size_t)b * Cc + m) * Hc + h,
                              acc[r][c][v]);
                }
            }
        }
}

// ---------------------------------------------------------------------------
// Workspace layout (~203 MiB, overlays exploit stream ordering):
//   off 0      : Akv bf16 (64 MiB)      -> later P3 fp32 stride-52 (13.6 MiB)
//   off 64 MiB : P1b bf16 (64 MiB)      -> later Vt bf16 (64 MiB)
//   off 128 MiB: (free; Sb eliminated — GEMM2/3 fused without atomics)
//   off 192 MiB: W1b, W2b (0.5 MiB each), W3b (64 KiB)
//   off 194 MiB: attnT bf16 32x64x2048 (8 MiB)
//   off 202 MiB: lens (128 B)
// ---------------------------------------------------------------------------
extern "C" void kernel_launch(void* const* d_in, const int* in_sizes, int n_in,
                              void* d_out, int out_size, void* d_ws, size_t ws_size,
                              hipStream_t stream)
{
    const float* keys     = (const float*)d_in[0];
    const float* vals     = (const float*)d_in[1];
    const int*   lens_raw = (const int*)d_in[2];
    const float* W1       = (const float*)d_in[3];
    const float* W2       = (const float*)d_in[4];
    const float* W3       = (const float*)d_in[5];

    char* ws = (char*)d_ws;
    const size_t MB = 1024 * 1024;
    unsigned short* Akv  = (unsigned short*)ws;
    float*          P3   = (float*)ws;                       // over Akv (dead)
    unsigned short* P1b  = (unsigned short*)(ws + 64 * MB);
    unsigned short* Vt   = (unsigned short*)(ws + 64 * MB);  // over P1b (dead)
    unsigned short* W1b  = (unsigned short*)(ws + 192 * MB);
    unsigned short* W2b  = W1b + Hc * Hc;
    unsigned short* W3b  = W2b + Hc * Hc;
    unsigned short* attnT= (unsigned short*)(ws + 194 * MB);
    int*            lens = (int*)(ws + 202 * MB);

    float* out_attn   = (float*)d_out;
    float* out_class  = out_attn + (size_t)Bc * Lc * Cc;
    float* out_smooth = out_class + (size_t)Bc * Cc * Hc;

    hipMemsetAsync(out_class, 0, (size_t)Bc * Cc * Hc * sizeof(float), stream);

    f32_to_bf16_kernel<<<(Mc * Hc / 8) / 256, 256, 0, stream>>>(keys, Akv);
    convert_weights_kernel<<<272, 256, 0, stream>>>(W1, W2, W3, W1b, W2b, W3b);
    normalize_lens_kernel<<<1, 64, 0, stream>>>(lens_raw, lens);

    // P1 = tanh(keys @ W1^T)   [bf16 out]
    mfma_gemm512<<<2048, 256, 0, stream>>>(Akv, W1b, P1b);
    // S = P1 + tanh(P1 @ W2^T) fused with P3 = S @ W3^T (block-local, no
    // atomics, no Sb round-trip). P3 overlays Akv (dead after gemm1).
    mfma_gemm2_fused<<<Mc / 64, 512, 0, stream>>>(P1b, W2b, W3b, P3);
    // Vt = transpose(bf16(vals))  (P1b dead now; Vt overlays it)
    transpose_v_kernel<<<dim3(Lc / 64, Hc / 64, Bc), 256, 0, stream>>>(vals, Vt);
    // pool + softmax + mask; also emits attnT bf16
    pool_softmax_kernel<<<Mc / 256, 256, 0, stream>>>(P3, lens, out_attn, out_smooth, attnT);
    // class_inputs = attnT @ Vt^T per batch (MFMA, K-split 4, atomic reduce)
    class_mfma_kernel<<<512, 256, 0, stream>>>(attnT, Vt, out_class);
}